// Round 14
// baseline (261.965 us; speedup 1.0000x reference)
//
#include <hip/hip_runtime.h>

// GeneralizedHamiltonianDynamics: bf16 MFMA pipeline
// B=32768, DIN=64, HID=1024
// K0:  merged weight prep
// K1:  h1 = tanh(z@W1+b1)             -> ws (bf16, row-major)
// K2:  gpre2 = W3*(1-tanh^2(h1@W2+b2)) -> gp2   [256^2 BK=64 GEMM, proven r10]
// K3:  gpre1 = (gpre2@W2^T)*(1-h1^2)  -> in-place over h1   [same GEMM]
// K1f: f1 = tanh(z@Wf1+bf1) -> gp2 (free after K3)
// K4p: P4[mb][q] = A_q(64 rows) @ B_q^T over k-quarter q    [2048 blocks, 4x K-split]
// K5:  out = bf2 + sum_q P4                                  [streaming combine]

typedef __attribute__((ext_vector_type(8))) short s16x8;
typedef __attribute__((ext_vector_type(4))) float f32x4;
typedef unsigned short u16;

#define DEVFN static __device__ __forceinline__

constexpr int DIN = 64;
constexpr int HID = 1024;

DEVFN u16 f2bf(float f) {
  unsigned u = __builtin_bit_cast(unsigned, f);
  u += 0x7fffu + ((u >> 16) & 1u);   // round-to-nearest-even
  return (u16)(u >> 16);
}
DEVFN float bf2f(u16 h) {
  unsigned u = ((unsigned)h) << 16;
  return __builtin_bit_cast(float, u);
}
DEVFN float fast_tanh(float x) {
  float e = __builtin_amdgcn_exp2f(x * 2.8853900817779268f);
  return 1.0f - 2.0f * __builtin_amdgcn_rcpf(e + 1.0f);
}
DEVFN f32x4 mfma16(s16x8 a, s16x8 b, f32x4 c) {
  return __builtin_amdgcn_mfma_f32_16x16x32_bf16(a, b, c, 0, 0, 0);
}

#define GLOAD16(g, l) __builtin_amdgcn_global_load_lds( \
    (const __attribute__((address_space(1))) unsigned int*)(const void*)(g), \
    (__attribute__((address_space(3))) unsigned int*)(void*)(l), 16, 0, 0)

// ---------------- K0: merged weight prep ----------------
__global__ __launch_bounds__(256) void k0_prep(
    const float* __restrict__ W2, const float* __restrict__ W1,
    const float* __restrict__ Wf1, const float* __restrict__ Wf2,
    u16* __restrict__ W2tp, u16* __restrict__ W2c,
    u16* __restrict__ W1p, u16* __restrict__ Wf1p,
    u16* __restrict__ W1s, u16* __restrict__ Wf2p) {
  __shared__ u16 tl[64 * 65];
  const int bi = blockIdx.x >> 4, bj = blockIdx.x & 15;
  const int tid = threadIdx.x;
#pragma unroll
  for (int i = 0; i < 16; ++i) {
    int idx = i * 256 + tid;
    int r = idx >> 6, c = idx & 63;
    float v = W2[(size_t)(bi * 64 + r) * 1024 + bj * 64 + c];
    u16 b = f2bf(v);
    W2c[(size_t)(bi * 64 + r) * 1024 + bj * 64 + c] = b;
    tl[r * 65 + c] = b;
  }
  __syncthreads();
#pragma unroll
  for (int i = 0; i < 16; ++i) {
    int idx = i * 256 + tid;
    int r = idx >> 6, c = idx & 63;
    W2tp[(size_t)(bj * 64 + r) * 1024 + bi * 64 + c] = tl[c * 65 + r];
  }
  int id = blockIdx.x * 256 + tid;     // < 65536
  int n = id >> 6, k = id & 63;
  W1p[id]  = f2bf(W1[k * HID + n]);
  Wf1p[id] = f2bf(Wf1[k * HID + n]);
  int nn = id >> 10, kk2 = id & 1023;
  float s = (nn < 32) ? 1.f : -1.f;
  W1s[id]  = f2bf(s * W1[((nn + 32) & 63) * HID + kk2]);
  Wf2p[id] = f2bf(Wf2[kk2 * DIN + nn]);
}

// ---------------- K1: out = tanh(z@Wp + b) ----------------
__global__ __launch_bounds__(256) void k1_h1(const float* z, const u16* Wp,
                                             const float* b, u16* o) {
  __shared__ __align__(16) u16 zl[64 * 72];
  const int tid = threadIdx.x;
  const int lane = tid & 63, w = tid >> 6;
  const int nb = blockIdx.x & 7, mb = blockIdx.x >> 3;
  const size_t m0 = (size_t)mb * 64;
  const int n0 = nb * 128;
#pragma unroll
  for (int c = 0; c < 4; ++c) {
    int i4 = c * 256 + tid;
    int row = i4 >> 4, col4 = (i4 & 15) * 4;
    f32x4 v = *reinterpret_cast<const f32x4*>(z + (m0 + row) * DIN + col4);
    u16* d = zl + row * 72 + col4;
    d[0] = f2bf(v[0]); d[1] = f2bf(v[1]); d[2] = f2bf(v[2]); d[3] = f2bf(v[3]);
  }
  __syncthreads();
  f32x4 acc[8] = {};
#pragma unroll
  for (int kk = 0; kk < 2; ++kk) {
    const int karr = kk * 32 + ((lane >> 4) << 3);
    s16x8 a = *reinterpret_cast<const s16x8*>(zl + (16 * w + (lane & 15)) * 72 + karr);
#pragma unroll
    for (int fn = 0; fn < 8; ++fn) {
      int n = n0 + fn * 16 + (lane & 15);
      s16x8 bb = *reinterpret_cast<const s16x8*>(Wp + (size_t)n * 64 + karr);
      acc[fn] = mfma16(a, bb, acc[fn]);
    }
  }
#pragma unroll
  for (int fn = 0; fn < 8; ++fn) {
    int n = n0 + fn * 16 + (lane & 15);
    float bias = b[n];
#pragma unroll
    for (int j = 0; j < 4; ++j) {
      size_t m = m0 + 16 * w + ((lane >> 4) << 2) + j;
      o[m * HID + n] = f2bf(fast_tanh(acc[fn][j] + bias));
    }
  }
}

// ---------------- K2/K3: 256x256-tile BK=64 2-phase pipelined GEMM (proven) ---
template <int MODE>
__global__ __launch_bounds__(512, 2) void k23_gemm(
    const u16* __restrict__ A, const u16* __restrict__ Bp,
    const float* __restrict__ b2, const float* __restrict__ W3,
    const u16* __restrict__ h1in, u16* __restrict__ outb) {
  extern __shared__ u16 lds[];  // 2 bufs x (A[256][64] + B[256][64]) = 65536 u16
  const int tid = threadIdx.x;
  const int lane = tid & 63, w = tid >> 6;
  const int wr = w >> 2, wc = w & 3;
  const int xcd = blockIdx.x & 7, local = blockIdx.x >> 3;
  const size_t m0 = (size_t)(xcd * 16 + (local >> 2)) * 256;
  const int n0 = (local & 3) * 256;

  const u16* gpa[4]; const u16* gpb[4]; int lo[4];
#pragma unroll
  for (int c = 0; c < 4; ++c) {
    int idx = c * 512 + tid, row = idx >> 3, cg = idx & 7;
    int sc = (cg ^ (row & 7)) << 3;
    gpa[c] = A + (m0 + row) * 1024 + sc;
    gpb[c] = Bp + (size_t)(n0 + row) * 1024 + sc;
    lo[c] = idx * 8;
  }
#define STAGE_A(B_, T_) { _Pragma("unroll") for (int c = 0; c < 4; ++c) \
    GLOAD16(gpa[c] + (T_) * 64, lds + (B_) * 32768 + lo[c]); }
#define STAGE_B(B_, T_) { _Pragma("unroll") for (int c = 0; c < 4; ++c) \
    GLOAD16(gpb[c] + (T_) * 64, lds + (B_) * 32768 + 16384 + lo[c]); }

  const int swz = (lane & 7) << 3;
  int aoff[8], boff[4];
#pragma unroll
  for (int i = 0; i < 8; ++i)
    aoff[i] = (wr * 128 + i * 16 + (lane & 15)) * 64 + ((lane >> 4) << 3);
#pragma unroll
  for (int j = 0; j < 4; ++j)
    boff[j] = (wc * 64 + j * 16 + (lane & 15)) * 64 + ((lane >> 4) << 3);

  f32x4 acc[8][4] = {};

#define PHASE(B_, KK_) { \
    s16x8 af[8], bf[4]; \
    _Pragma("unroll") for (int i = 0; i < 8; ++i) \
      af[i] = *reinterpret_cast<const s16x8*>(lds + (B_) * 32768 + ((aoff[i] + (KK_) * 32) ^ swz)); \
    _Pragma("unroll") for (int j = 0; j < 4; ++j) \
      bf[j] = *reinterpret_cast<const s16x8*>(lds + (B_) * 32768 + 16384 + ((boff[j] + (KK_) * 32) ^ swz)); \
    __builtin_amdgcn_s_setprio(1); \
    _Pragma("unroll") for (int i = 0; i < 8; ++i) { \
      _Pragma("unroll") for (int j = 0; j < 4; ++j) \
        acc[i][j] = mfma16(af[i], bf[j], acc[i][j]); } \
    __builtin_amdgcn_s_setprio(0); }

  STAGE_A(0, 0); STAGE_B(0, 0);
  for (int t = 0; t < 15; ++t) {
    const int cur = t & 1, nxt = cur ^ 1;
    STAGE_A(nxt, t + 1);
    asm volatile("s_waitcnt vmcnt(4)" ::: "memory");
    __builtin_amdgcn_s_barrier();
    asm volatile("" ::: "memory");
    PHASE(cur, 0);
    STAGE_B(nxt, t + 1);
    PHASE(cur, 1);
    asm volatile("" ::: "memory");
    __builtin_amdgcn_s_barrier();
    asm volatile("" ::: "memory");
  }
  asm volatile("s_waitcnt vmcnt(0)" ::: "memory");
  __builtin_amdgcn_s_barrier();
  asm volatile("" ::: "memory");
  PHASE(1, 0);
  PHASE(1, 1);
  asm volatile("" ::: "memory");
  __builtin_amdgcn_s_barrier();
  asm volatile("" ::: "memory");

  const int wbase = w * 8192;
  float b2v[4], w3v[4];
  if (MODE == 0) {
#pragma unroll
    for (int j = 0; j < 4; ++j) {
      int n = n0 + wc * 64 + j * 16 + (lane & 15);
      b2v[j] = b2[n]; w3v[j] = W3[n];
    }
  }
#pragma unroll
  for (int h = 0; h < 2; ++h) {
    if (h == 1) asm volatile("s_waitcnt lgkmcnt(0)" ::: "memory");
#pragma unroll
    for (int ip = 0; ip < 4; ++ip) {
#pragma unroll
      for (int j = 0; j < 4; ++j) {
#pragma unroll
        for (int r = 0; r < 4; ++r) {
          float v = acc[h * 4 + ip][j][r];
          u16 o;
          if (MODE == 0) {
            float tt = fast_tanh(v + b2v[j]);
            o = f2bf(w3v[j] * (1.f - tt * tt));
          } else {
            o = f2bf(v);
          }
          int lr = ip * 16 + ((lane >> 4) << 2) + r;
          lds[wbase + lr * 64 + j * 16 + (lane & 15)] = o;
        }
      }
    }
#pragma unroll
    for (int r8 = 0; r8 < 8; ++r8) {
      int lr = r8 * 8 + (lane >> 3), c8 = (lane & 7) * 8;
      s16x8 vv = *reinterpret_cast<const s16x8*>(lds + wbase + lr * 64 + c8);
      size_t grow = m0 + wr * 128 + h * 64 + lr;
      int gcol = n0 + wc * 64 + c8;
      if (MODE == 1) {
        s16x8 hh = *reinterpret_cast<const s16x8*>(h1in + grow * 1024 + gcol);
#pragma unroll
        for (int e = 0; e < 8; ++e) {
          float hv = bf2f((u16)hh[e]);
          vv[e] = (short)f2bf(bf2f((u16)vv[e]) * (1.f - hv * hv));
        }
      }
      *reinterpret_cast<s16x8*>(outb + grow * 1024 + gcol) = vv;
    }
  }
#undef STAGE_A
#undef STAGE_B
#undef PHASE
}

// ---------------- K4p: 4x K-split partial GEMM ----------------
// Grid 2048 = 512 m-tiles x 4 k-quarters. Quarter q: q<2 -> gp1 x W1s,
// else f1 x Wf2p; k-offset (q&1)*512 within the [64][1024] source pair.
// Each block: proven double-buffered vmcnt(4) loop over 8 K-tiles of 64;
// writes P4[mb][q][64][64] fp32. 32KB LDS -> ~5 blocks/CU (high TLP).
__global__ __launch_bounds__(256) void k4_part(
    const u16* __restrict__ gp1, const u16* __restrict__ f1,
    const u16* __restrict__ W1s, const u16* __restrict__ Wf2p,
    float* __restrict__ P4) {
  __shared__ __align__(16) u16 Ab[2][4096];
  __shared__ __align__(16) u16 Bb[2][4096];
  const int tid = threadIdx.x;
  const int lane = tid & 63, w = tid >> 6;
  const int lr = lane & 15, g = lane >> 4;
  const int q = blockIdx.x & 3;
  const size_t mb = blockIdx.x >> 2;
  const size_t m0 = mb * 64;
  const u16* asrc = (q < 2) ? gp1 : f1;
  const u16* bsrc = (q < 2) ? W1s : Wf2p;
  const int koff = (q & 1) * 512;

  size_t aoffs[2]; int boffs[2], lo[2];
#pragma unroll
  for (int c = 0; c < 2; ++c) {
    int idx = c * 256 + tid;          // 0..511 16B-chunks per tile
    int row = idx >> 3, cg = idx & 7;
    int sc = (cg ^ (row & 7)) << 3;
    aoffs[c] = (m0 + row) * 1024 + koff + sc;
    boffs[c] = row * 1024 + koff + sc;
    lo[c] = idx * 8;
  }
#define K4STAGE(B_, T_) { \
    _Pragma("unroll") for (int c = 0; c < 2; ++c) { \
      GLOAD16(asrc + aoffs[c] + (T_) * 64, Ab[B_] + lo[c]); \
      GLOAD16(bsrc + boffs[c] + (T_) * 64, Bb[B_] + lo[c]); } }

  const int arow = w * 16 + lr;
  int afr[2], bfr[2][4];
#pragma unroll
  for (int kkl = 0; kkl < 2; ++kkl) {
    afr[kkl] = arow * 64 + ((kkl * 32 + g * 8) ^ ((arow & 7) << 3));
#pragma unroll
    for (int fn = 0; fn < 4; ++fn) {
      int br = fn * 16 + lr;
      bfr[kkl][fn] = br * 64 + ((kkl * 32 + g * 8) ^ ((br & 7) << 3));
    }
  }

  f32x4 acc[4] = {};
#define K4MM(BUF_) { \
    _Pragma("unroll") for (int kkl = 0; kkl < 2; ++kkl) { \
      s16x8 a = *reinterpret_cast<const s16x8*>(Ab[BUF_] + afr[kkl]); \
      _Pragma("unroll") for (int fn = 0; fn < 4; ++fn) { \
        s16x8 b = *reinterpret_cast<const s16x8*>(Bb[BUF_] + bfr[kkl][fn]); \
        acc[fn] = mfma16(a, b, acc[fn]); } } }
#define TBAR() { asm volatile("" ::: "memory"); __builtin_amdgcn_s_barrier(); asm volatile("" ::: "memory"); }

  K4STAGE(0, 0);
  for (int t = 0; t < 7; ++t) {
    K4STAGE((t + 1) & 1, t + 1);
    asm volatile("s_waitcnt vmcnt(4)" ::: "memory"); // retire tile t's 4 loads
    TBAR();
    K4MM(t & 1);
    TBAR();
  }
  asm volatile("s_waitcnt vmcnt(0)" ::: "memory");
  TBAR();
  K4MM(1);

  float* Pp = P4 + (mb * 4 + q) * 4096;
#pragma unroll
  for (int fn = 0; fn < 4; ++fn)
#pragma unroll
    for (int j = 0; j < 4; ++j)
      Pp[(w * 16 + g * 4 + j) * 64 + fn * 16 + lr] = acc[fn][j];
#undef K4STAGE
#undef K4MM
#undef TBAR
}

// ---------------- K5: streaming combine ----------------
// out[m][n] = bf2[n] + sum_q P4[m>>6][q][m&63][n]; one float4 per thread.
__global__ __launch_bounds__(256) void k5_combine(
    const float* __restrict__ P4, const float* __restrict__ bf2,
    float* __restrict__ out) {
  int fi = blockIdx.x * 256 + threadIdx.x;     // 0..524287 float4 groups
  int m = fi >> 4, c4 = (fi & 15) * 4;
  size_t base = (size_t)(m >> 6) * 16384 + (size_t)(m & 63) * 64 + c4;
  f32x4 s = *reinterpret_cast<const f32x4*>(bf2 + c4);
#pragma unroll
  for (int qq = 0; qq < 4; ++qq) {
    f32x4 p = *reinterpret_cast<const f32x4*>(P4 + base + qq * 4096);
    s[0] += p[0]; s[1] += p[1]; s[2] += p[2]; s[3] += p[3];
  }
  *reinterpret_cast<f32x4*>(out + (size_t)m * 64 + c4) = s;
}

extern "C" void kernel_launch(void* const* d_in, const int* in_sizes, int n_in,
                              void* d_out, int out_size, void* d_ws, size_t ws_size,
                              hipStream_t stream) {
  const float* z   = (const float*)d_in[0];
  const float* W1  = (const float*)d_in[1];
  const float* b1  = (const float*)d_in[2];
  const float* W2  = (const float*)d_in[3];
  const float* b2  = (const float*)d_in[4];
  const float* W3  = (const float*)d_in[5];
  const float* Wf1 = (const float*)d_in[7];
  const float* bf1 = (const float*)d_in[8];
  const float* Wf2 = (const float*)d_in[9];
  const float* bf2 = (const float*)d_in[10];

  char* ws = (char*)d_ws;
  u16* W1p  = (u16*)(ws + 0);          // 128KB
  u16* Wf1p = (u16*)(ws + 131072);     // 128KB
  u16* W2tp = (u16*)(ws + 262144);     // 2MB
  u16* W2c  = (u16*)(ws + 2359296);    // 2MB
  u16* W1s  = (u16*)(ws + 4456448);    // 128KB (symplectic-folded W1)
  u16* Wf2p = (u16*)(ws + 4587520);    // 128KB
  u16* h1   = (u16*)(ws + 4718592);                        // 64MB (-> gpre1 in-place)
  u16* gp2  = (u16*)(ws + 4718592 + 67108864ull);          // 64MB (gpre2 -> f1)
  float* P4 = (float*)(ws + 4718592 + 2ull * 67108864ull); // 32MB partials
  float* out = (float*)d_out;

  k0_prep<<<256, 256, 0, stream>>>(W2, W1, Wf1, Wf2, W2tp, W2c, W1p, Wf1p, W1s, Wf2p);
  k1_h1<<<4096, 256, 0, stream>>>(z, W1p, b1, h1);
  k23_gemm<0><<<512, 512, 131072, stream>>>(h1, W2tp, b2, W3, nullptr, gp2);
  k23_gemm<1><<<512, 512, 131072, stream>>>(gp2, W2c, nullptr, nullptr, h1, h1);
  k1_h1<<<4096, 256, 0, stream>>>(z, Wf1p, bf1, gp2);   // f1 -> gp2
  k4_part<<<2048, 256, 0, stream>>>(h1, gp2, W1s, Wf2p, P4);
  k5_combine<<<2048, 256, 0, stream>>>(P4, bf2, out);
}

// Round 15
// 250.983 us; speedup vs baseline: 1.0438x; 1.0438x over previous
//
#include <hip/hip_runtime.h>

// GeneralizedHamiltonianDynamics: bf16 MFMA pipeline  (consolidated best: r10)
// B=32768, DIN=64, HID=1024
// K0:  merged weight prep (W2 LDS-transpose pack + small packs)
// K1:  h1 = tanh(z@W1+b1)             -> ws (bf16)
// K2:  gpre2 = W3*(1-tanh^2(h1@W2+b2)) -> gp2  [256^2 BK=64 2-phase GEMM, proven]
// K3:  gpre1 = (gpre2@W2^T)*(1-h1^2)  -> in-place over h1  [same GEMM]
// K1f: f1 = tanh(z@Wf1+bf1) -> gp2 (free after K3)
// K4:  out = [gp1|f1] @ [W1s|Wf2p]^T + bf2  (8-wave K-split streaming GEMM)

typedef __attribute__((ext_vector_type(8))) short s16x8;
typedef __attribute__((ext_vector_type(4))) float f32x4;
typedef unsigned short u16;

#define DEVFN static __device__ __forceinline__

constexpr int DIN = 64;
constexpr int HID = 1024;

DEVFN u16 f2bf(float f) {
  unsigned u = __builtin_bit_cast(unsigned, f);
  u += 0x7fffu + ((u >> 16) & 1u);   // round-to-nearest-even
  return (u16)(u >> 16);
}
DEVFN float bf2f(u16 h) {
  unsigned u = ((unsigned)h) << 16;
  return __builtin_bit_cast(float, u);
}
DEVFN float fast_tanh(float x) {
  float e = __builtin_amdgcn_exp2f(x * 2.8853900817779268f);
  return 1.0f - 2.0f * __builtin_amdgcn_rcpf(e + 1.0f);
}
DEVFN f32x4 mfma16(s16x8 a, s16x8 b, f32x4 c) {
  return __builtin_amdgcn_mfma_f32_16x16x32_bf16(a, b, c, 0, 0, 0);
}

#define GLOAD16(g, l) __builtin_amdgcn_global_load_lds( \
    (const __attribute__((address_space(1))) unsigned int*)(const void*)(g), \
    (__attribute__((address_space(3))) unsigned int*)(void*)(l), 16, 0, 0)

// ---------------- K0: merged weight prep ----------------
__global__ __launch_bounds__(256) void k0_prep(
    const float* __restrict__ W2, const float* __restrict__ W1,
    const float* __restrict__ Wf1, const float* __restrict__ Wf2,
    u16* __restrict__ W2tp, u16* __restrict__ W2c,
    u16* __restrict__ W1p, u16* __restrict__ Wf1p,
    u16* __restrict__ W1s, u16* __restrict__ Wf2p) {
  __shared__ u16 tl[64 * 65];
  const int bi = blockIdx.x >> 4, bj = blockIdx.x & 15;
  const int tid = threadIdx.x;
#pragma unroll
  for (int i = 0; i < 16; ++i) {
    int idx = i * 256 + tid;
    int r = idx >> 6, c = idx & 63;
    float v = W2[(size_t)(bi * 64 + r) * 1024 + bj * 64 + c];
    u16 b = f2bf(v);
    W2c[(size_t)(bi * 64 + r) * 1024 + bj * 64 + c] = b;
    tl[r * 65 + c] = b;
  }
  __syncthreads();
#pragma unroll
  for (int i = 0; i < 16; ++i) {
    int idx = i * 256 + tid;
    int r = idx >> 6, c = idx & 63;
    W2tp[(size_t)(bj * 64 + r) * 1024 + bi * 64 + c] = tl[c * 65 + r];
  }
  int id = blockIdx.x * 256 + tid;     // < 65536
  int n = id >> 6, k = id & 63;
  W1p[id]  = f2bf(W1[k * HID + n]);
  Wf1p[id] = f2bf(Wf1[k * HID + n]);
  int nn = id >> 10, kk2 = id & 1023;
  float s = (nn < 32) ? 1.f : -1.f;
  W1s[id]  = f2bf(s * W1[((nn + 32) & 63) * HID + kk2]);
  Wf2p[id] = f2bf(Wf2[kk2 * DIN + nn]);
}

// ---------------- K1: out = tanh(z@Wp + b) ----------------
__global__ __launch_bounds__(256) void k1_h1(const float* z, const u16* Wp,
                                             const float* b, u16* o) {
  __shared__ __align__(16) u16 zl[64 * 72];
  const int tid = threadIdx.x;
  const int lane = tid & 63, w = tid >> 6;
  const int nb = blockIdx.x & 7, mb = blockIdx.x >> 3;
  const size_t m0 = (size_t)mb * 64;
  const int n0 = nb * 128;
#pragma unroll
  for (int c = 0; c < 4; ++c) {
    int i4 = c * 256 + tid;
    int row = i4 >> 4, col4 = (i4 & 15) * 4;
    f32x4 v = *reinterpret_cast<const f32x4*>(z + (m0 + row) * DIN + col4);
    u16* d = zl + row * 72 + col4;
    d[0] = f2bf(v[0]); d[1] = f2bf(v[1]); d[2] = f2bf(v[2]); d[3] = f2bf(v[3]);
  }
  __syncthreads();
  f32x4 acc[8] = {};
#pragma unroll
  for (int kk = 0; kk < 2; ++kk) {
    const int karr = kk * 32 + ((lane >> 4) << 3);
    s16x8 a = *reinterpret_cast<const s16x8*>(zl + (16 * w + (lane & 15)) * 72 + karr);
#pragma unroll
    for (int fn = 0; fn < 8; ++fn) {
      int n = n0 + fn * 16 + (lane & 15);
      s16x8 bb = *reinterpret_cast<const s16x8*>(Wp + (size_t)n * 64 + karr);
      acc[fn] = mfma16(a, bb, acc[fn]);
    }
  }
#pragma unroll
  for (int fn = 0; fn < 8; ++fn) {
    int n = n0 + fn * 16 + (lane & 15);
    float bias = b[n];
#pragma unroll
    for (int j = 0; j < 4; ++j) {
      size_t m = m0 + 16 * w + ((lane >> 4) << 2) + j;
      o[m * HID + n] = f2bf(fast_tanh(acc[fn][j] + bias));
    }
  }
}

// ---------------- K2/K3: 256x256-tile BK=64 2-phase pipelined GEMM (proven) ---
template <int MODE>
__global__ __launch_bounds__(512, 2) void k23_gemm(
    const u16* __restrict__ A, const u16* __restrict__ Bp,
    const float* __restrict__ b2, const float* __restrict__ W3,
    const u16* __restrict__ h1in, u16* __restrict__ outb) {
  extern __shared__ u16 lds[];  // 2 bufs x (A[256][64] + B[256][64]) = 65536 u16
  const int tid = threadIdx.x;
  const int lane = tid & 63, w = tid >> 6;
  const int wr = w >> 2, wc = w & 3;
  const int xcd = blockIdx.x & 7, local = blockIdx.x >> 3;
  const size_t m0 = (size_t)(xcd * 16 + (local >> 2)) * 256;
  const int n0 = (local & 3) * 256;

  const u16* gpa[4]; const u16* gpb[4]; int lo[4];
#pragma unroll
  for (int c = 0; c < 4; ++c) {
    int idx = c * 512 + tid, row = idx >> 3, cg = idx & 7;
    int sc = (cg ^ (row & 7)) << 3;
    gpa[c] = A + (m0 + row) * 1024 + sc;
    gpb[c] = Bp + (size_t)(n0 + row) * 1024 + sc;
    lo[c] = idx * 8;
  }
#define STAGE_A(B_, T_) { _Pragma("unroll") for (int c = 0; c < 4; ++c) \
    GLOAD16(gpa[c] + (T_) * 64, lds + (B_) * 32768 + lo[c]); }
#define STAGE_B(B_, T_) { _Pragma("unroll") for (int c = 0; c < 4; ++c) \
    GLOAD16(gpb[c] + (T_) * 64, lds + (B_) * 32768 + 16384 + lo[c]); }

  const int swz = (lane & 7) << 3;
  int aoff[8], boff[4];
#pragma unroll
  for (int i = 0; i < 8; ++i)
    aoff[i] = (wr * 128 + i * 16 + (lane & 15)) * 64 + ((lane >> 4) << 3);
#pragma unroll
  for (int j = 0; j < 4; ++j)
    boff[j] = (wc * 64 + j * 16 + (lane & 15)) * 64 + ((lane >> 4) << 3);

  f32x4 acc[8][4] = {};

#define PHASE(B_, KK_) { \
    s16x8 af[8], bf[4]; \
    _Pragma("unroll") for (int i = 0; i < 8; ++i) \
      af[i] = *reinterpret_cast<const s16x8*>(lds + (B_) * 32768 + ((aoff[i] + (KK_) * 32) ^ swz)); \
    _Pragma("unroll") for (int j = 0; j < 4; ++j) \
      bf[j] = *reinterpret_cast<const s16x8*>(lds + (B_) * 32768 + 16384 + ((boff[j] + (KK_) * 32) ^ swz)); \
    __builtin_amdgcn_s_setprio(1); \
    _Pragma("unroll") for (int i = 0; i < 8; ++i) { \
      _Pragma("unroll") for (int j = 0; j < 4; ++j) \
        acc[i][j] = mfma16(af[i], bf[j], acc[i][j]); } \
    __builtin_amdgcn_s_setprio(0); }

  STAGE_A(0, 0); STAGE_B(0, 0);
  for (int t = 0; t < 15; ++t) {
    const int cur = t & 1, nxt = cur ^ 1;
    STAGE_A(nxt, t + 1);
    asm volatile("s_waitcnt vmcnt(4)" ::: "memory");
    __builtin_amdgcn_s_barrier();
    asm volatile("" ::: "memory");
    PHASE(cur, 0);
    STAGE_B(nxt, t + 1);
    PHASE(cur, 1);
    asm volatile("" ::: "memory");
    __builtin_amdgcn_s_barrier();
    asm volatile("" ::: "memory");
  }
  asm volatile("s_waitcnt vmcnt(0)" ::: "memory");
  __builtin_amdgcn_s_barrier();
  asm volatile("" ::: "memory");
  PHASE(1, 0);
  PHASE(1, 1);
  asm volatile("" ::: "memory");
  __builtin_amdgcn_s_barrier();
  asm volatile("" ::: "memory");

  const int wbase = w * 8192;
  float b2v[4], w3v[4];
  if (MODE == 0) {
#pragma unroll
    for (int j = 0; j < 4; ++j) {
      int n = n0 + wc * 64 + j * 16 + (lane & 15);
      b2v[j] = b2[n]; w3v[j] = W3[n];
    }
  }
#pragma unroll
  for (int h = 0; h < 2; ++h) {
    if (h == 1) asm volatile("s_waitcnt lgkmcnt(0)" ::: "memory");
#pragma unroll
    for (int ip = 0; ip < 4; ++ip) {
#pragma unroll
      for (int j = 0; j < 4; ++j) {
#pragma unroll
        for (int r = 0; r < 4; ++r) {
          float v = acc[h * 4 + ip][j][r];
          u16 o;
          if (MODE == 0) {
            float tt = fast_tanh(v + b2v[j]);
            o = f2bf(w3v[j] * (1.f - tt * tt));
          } else {
            o = f2bf(v);
          }
          int lr = ip * 16 + ((lane >> 4) << 2) + r;
          lds[wbase + lr * 64 + j * 16 + (lane & 15)] = o;
        }
      }
    }
#pragma unroll
    for (int r8 = 0; r8 < 8; ++r8) {
      int lr = r8 * 8 + (lane >> 3), c8 = (lane & 7) * 8;
      s16x8 vv = *reinterpret_cast<const s16x8*>(lds + wbase + lr * 64 + c8);
      size_t grow = m0 + wr * 128 + h * 64 + lr;
      int gcol = n0 + wc * 64 + c8;
      if (MODE == 1) {
        s16x8 hh = *reinterpret_cast<const s16x8*>(h1in + grow * 1024 + gcol);
#pragma unroll
        for (int e = 0; e < 8; ++e) {
          float hv = bf2f((u16)hh[e]);
          vv[e] = (short)f2bf(bf2f((u16)vv[e]) * (1.f - hv * hv));
        }
      }
      *reinterpret_cast<s16x8*>(outb + grow * 1024 + gcol) = vv;
    }
  }
#undef STAGE_A
#undef STAGE_B
#undef PHASE
}

// ---------------- K4 v5b: 8-wave K-split streaming GEMM (proven r9/r10) ------
// out[m][n] = sum_{k<2048} Acat[m][k]*Bcat[n][k] + bf2[n]
// 512 threads = 2 groups x 4 waves. Group 0: gp1 x W1s; group 1: f1 x Wf2p
// (local k-tiles 0-15 each). Double-buffered vmcnt(4) loop; LDS reduce at end.
__global__ __launch_bounds__(512) void k4_gemm(
    const u16* __restrict__ gp1, const u16* __restrict__ f1,
    const u16* __restrict__ W1s, const u16* __restrict__ Wf2p,
    const float* __restrict__ bf2, float* __restrict__ out) {
  __shared__ __align__(16) u16 Ab[2][2][4096];   // [grp][buf][64x64] swizzled
  __shared__ __align__(16) u16 Bb[2][2][4096];
  const int tid = threadIdx.x;
  const int w8 = tid >> 6, lane = tid & 63;
  const int grp = w8 >> 2, w = w8 & 3;
  const int gt = tid & 255;
  const int lr = lane & 15, g = lane >> 4;
  const size_t m0 = (size_t)blockIdx.x * 64;
  const u16* asrc = grp ? f1 : gp1;      // each buffer is [32768][1024]
  const u16* bsrc = grp ? Wf2p : W1s;    // each is [64][1024]

  int aoffs[2], boffs[2], lo[2];
#pragma unroll
  for (int c = 0; c < 2; ++c) {
    int idx = c * 256 + gt;           // 0..511 16B-chunks per tile
    int row = idx >> 3, cg = idx & 7;
    aoffs[c] = (int)((m0 + row) * 1024) + ((cg ^ (row & 7)) << 3);
    boffs[c] = row * 1024 + ((cg ^ (row & 7)) << 3);
    lo[c] = idx * 8;
  }
#define K4STAGE(B_, T_) { const int ko_ = (T_) * 64; \
    _Pragma("unroll") for (int c = 0; c < 2; ++c) { \
      GLOAD16(asrc + aoffs[c] + ko_, Ab[grp][B_] + lo[c]); \
      GLOAD16(bsrc + boffs[c] + ko_, Bb[grp][B_] + lo[c]); } }

  const int arow = w * 16 + lr;
  int afr[2], bfr[2][4];
#pragma unroll
  for (int kkl = 0; kkl < 2; ++kkl) {
    afr[kkl] = arow * 64 + ((kkl * 32 + g * 8) ^ ((arow & 7) << 3));
#pragma unroll
    for (int fn = 0; fn < 4; ++fn) {
      int br = fn * 16 + lr;
      bfr[kkl][fn] = br * 64 + ((kkl * 32 + g * 8) ^ ((br & 7) << 3));
    }
  }

  f32x4 acc[4] = {};
#define K4MM(BUF_) { \
    _Pragma("unroll") for (int kkl = 0; kkl < 2; ++kkl) { \
      s16x8 a = *reinterpret_cast<const s16x8*>(Ab[grp][BUF_] + afr[kkl]); \
      _Pragma("unroll") for (int fn = 0; fn < 4; ++fn) { \
        s16x8 b = *reinterpret_cast<const s16x8*>(Bb[grp][BUF_] + bfr[kkl][fn]); \
        acc[fn] = mfma16(a, b, acc[fn]); } } }
#define TBAR() { asm volatile("" ::: "memory"); __builtin_amdgcn_s_barrier(); asm volatile("" ::: "memory"); }

  K4STAGE(0, 0);
  for (int t = 0; t < 15; ++t) {
    K4STAGE((t + 1) & 1, t + 1);
    asm volatile("s_waitcnt vmcnt(4)" ::: "memory"); // retire tile t's 4 loads
    TBAR();
    K4MM(t & 1);
    TBAR();
  }
  asm volatile("s_waitcnt vmcnt(0)" ::: "memory");
  TBAR();
  K4MM(1);

  // cross-group reduction through LDS (reuse Ab as 16KB float buffer)
  __syncthreads();
  float* red = (float*)&Ab[0][0][0];
  if (grp == 1) {
#pragma unroll
    for (int fn = 0; fn < 4; ++fn)
#pragma unroll
      for (int j = 0; j < 4; ++j)
        red[(fn * 4 + j) * 256 + gt] = acc[fn][j];
  }
  __syncthreads();
  if (grp == 0) {
#pragma unroll
    for (int fn = 0; fn < 4; ++fn) {
      int n = fn * 16 + lr;
      float bias = bf2[n];
#pragma unroll
      for (int j = 0; j < 4; ++j) {
        float v = acc[fn][j] + red[(fn * 4 + j) * 256 + gt] + bias;
        size_t m = m0 + w * 16 + g * 4 + j;
        out[m * DIN + n] = v;
      }
    }
  }
#undef K4STAGE
#undef K4MM
#undef TBAR
}

extern "C" void kernel_launch(void* const* d_in, const int* in_sizes, int n_in,
                              void* d_out, int out_size, void* d_ws, size_t ws_size,
                              hipStream_t stream) {
  const float* z   = (const float*)d_in[0];
  const float* W1  = (const float*)d_in[1];
  const float* b1  = (const float*)d_in[2];
  const float* W2  = (const float*)d_in[3];
  const float* b2  = (const float*)d_in[4];
  const float* W3  = (const float*)d_in[5];
  const float* Wf1 = (const float*)d_in[7];
  const float* bf1 = (const float*)d_in[8];
  const float* Wf2 = (const float*)d_in[9];
  const float* bf2 = (const float*)d_in[10];

  char* ws = (char*)d_ws;
  u16* W1p  = (u16*)(ws + 0);          // 128KB
  u16* Wf1p = (u16*)(ws + 131072);     // 128KB
  u16* W2tp = (u16*)(ws + 262144);     // 2MB
  u16* W2c  = (u16*)(ws + 2359296);    // 2MB
  u16* W1s  = (u16*)(ws + 4456448);    // 128KB (symplectic-folded W1)
  u16* Wf2p = (u16*)(ws + 4587520);    // 128KB
  u16* h1   = (u16*)(ws + 4718592);                        // 64MB (-> gpre1 in-place)
  u16* gp2  = (u16*)(ws + 4718592 + 67108864ull);          // 64MB (gpre2 -> f1)
  float* out = (float*)d_out;

  k0_prep<<<256, 256, 0, stream>>>(W2, W1, Wf1, Wf2, W2tp, W2c, W1p, Wf1p, W1s, Wf2p);
  k1_h1<<<4096, 256, 0, stream>>>(z, W1p, b1, h1);
  k23_gemm<0><<<512, 512, 131072, stream>>>(h1, W2tp, b2, W3, nullptr, gp2);
  k23_gemm<1><<<512, 512, 131072, stream>>>(gp2, W2c, nullptr, nullptr, h1, h1);
  k1_h1<<<4096, 256, 0, stream>>>(z, Wf1p, bf1, gp2);   // f1 -> gp2
  k4_gemm<<<512, 512, 0, stream>>>(h1, gp2, W1s, Wf2p, bf2, out);
}